// Round 6
// baseline (257.976 us; speedup 1.0000x reference)
//
#include <hip/hip_runtime.h>
#include <hip/hip_bf16.h>
#include <math.h>

// Problem shape (SimpleGCN):
//   node_features [N=100000, 128] f32
//   edge_index    [2, E=1200000] i32   (row 0 = src, row 1 = dst)
//   post_mask     [P=50000] i32
//   W_enc [128,64] b_enc [64]  W_conv [64,64] b_conv [64]  W_out [64,1] b_out [1]
// out[p] = sigmoid( relu( (emb + segsum(emb[src]->dst))[post[p]] @ Wc + bc ) @ Wo + bo )
//
// Round-5 lessons: (1) k_head uses the same "VGPR weight array" idiom the
// allocator demonstrably sinks (round-4: VGPR=68, 120 us) -> replace with
// MFMA fused into the gather; (2) 11 serialized dispatches -> cut to 8
// (decoupled-lookback scan replaces scan1/2/3+cursor; gather+conv+head fused).

#define HIDDEN 64
#define NODE_DIM 128
#define SCAN_CHUNK 1024   // 256 threads x 4 elements per scan block
#define LDSROW 68         // LDS row stride (floats): 16B-aligned, 2-way banks

typedef __attribute__((ext_vector_type(8))) short short8;   // 8 bf16 (4 VGPR)
typedef __attribute__((ext_vector_type(4))) float floatx4;  // mfma C/D frag

union F2B { short8 s; __hip_bfloat162 h[4]; };

__device__ inline short8 cvt8(const float4& p, const float4& q) {
    F2B u;
    u.h[0] = __float22bfloat162_rn(make_float2(p.x, p.y));
    u.h[1] = __float22bfloat162_rn(make_float2(p.z, p.w));
    u.h[2] = __float22bfloat162_rn(make_float2(q.x, q.y));
    u.h[3] = __float22bfloat162_rn(make_float2(q.z, q.w));
    return u.s;
}

// hi/lo bf16 split of 8 floats: hi = bf16(x), lo = bf16(x - float(hi)).
__device__ inline void cvt8_split(const float4& p, const float4& q,
                                  short8& hi, short8& lo) {
    const float f[8] = {p.x, p.y, p.z, p.w, q.x, q.y, q.z, q.w};
    F2B uh, ul;
    #pragma unroll
    for (int jj = 0; jj < 4; ++jj) {
        const float2 v = make_float2(f[2 * jj], f[2 * jj + 1]);
        const __hip_bfloat162 h = __float22bfloat162_rn(v);
        const float2 hv = __bfloat1622float2(h);
        ul.h[jj] = __float22bfloat162_rn(make_float2(v.x - hv.x, v.y - hv.y));
        uh.h[jj] = h;
    }
    hi = uh.s; lo = ul.s;
}

// ---------------------------------------------------------------------------
// Stage 1 (MFMA): emb = relu(A @ W_enc + b_enc).
// Wave = 16-node M-tile: 4 ksteps x 4 ntiles of 16x16x32 bf16 mfma.
// ---------------------------------------------------------------------------
__global__ __launch_bounds__(256) void k_encode_mfma(
    const float* __restrict__ A, const float* __restrict__ We,
    const float* __restrict__ be, float* __restrict__ emb, int n_tiles)
{
    const int lane = threadIdx.x & 63;
    const int r    = lane & 15;
    const int quad = lane >> 4;

    short8 Wb[4][4];   // [kstep][ntile], built once per wave
    #pragma unroll
    for (int ks = 0; ks < 4; ++ks) {
        #pragma unroll
        for (int nt = 0; nt < 4; ++nt) {
            F2B u;
            #pragma unroll
            for (int jj = 0; jj < 4; ++jj) {
                const int k0 = ks * 32 + quad * 8 + 2 * jj;
                const float lo = We[(size_t)k0 * HIDDEN + nt * 16 + r];
                const float hi = We[(size_t)(k0 + 1) * HIDDEN + nt * 16 + r];
                u.h[jj] = __float22bfloat162_rn(make_float2(lo, hi));
            }
            Wb[ks][nt] = u.s;
        }
    }
    float bias[4];
    #pragma unroll
    for (int nt = 0; nt < 4; ++nt) bias[nt] = be[nt * 16 + r];

    const int wid    = (blockIdx.x * 256 + threadIdx.x) >> 6;
    const int nwaves = gridDim.x * 4;
    for (int t = wid; t < n_tiles; t += nwaves) {
        const float* Arow = A + (size_t)t * 16 * NODE_DIM + (size_t)r * NODE_DIM + quad * 8;
        float4 a[4][2];
        #pragma unroll
        for (int ks = 0; ks < 4; ++ks) {
            a[ks][0] = *(const float4*)(Arow + ks * 32);
            a[ks][1] = *(const float4*)(Arow + ks * 32 + 4);
        }
        floatx4 acc[4] = {};
        #pragma unroll
        for (int ks = 0; ks < 4; ++ks) {
            const short8 af = cvt8(a[ks][0], a[ks][1]);
            #pragma unroll
            for (int nt = 0; nt < 4; ++nt)
                acc[nt] = __builtin_amdgcn_mfma_f32_16x16x32_bf16(af, Wb[ks][nt], acc[nt], 0, 0, 0);
        }
        #pragma unroll
        for (int nt = 0; nt < 4; ++nt) {
            #pragma unroll
            for (int g = 0; g < 4; ++g) {
                const int node = t * 16 + quad * 4 + g;
                const float h = fmaxf(acc[nt][g] + bias[nt], 0.0f);
                emb[(size_t)node * HIDDEN + nt * 16 + r] = h;
            }
        }
    }
}

// Tail nodes (n_nodes % 16) — plain vector path (not launched for 100000).
__global__ __launch_bounds__(64) void k_encode_tail(
    const float* __restrict__ A, const float* __restrict__ We,
    const float* __restrict__ be, float* __restrict__ emb, int base)
{
    const int lane = threadIdx.x;
    const int n = base + blockIdx.x;
    const float* row = A + (size_t)n * NODE_DIM;
    float acc = be[lane];
    for (int k = 0; k < NODE_DIM; ++k)
        acc = fmaf(row[k], We[(size_t)k * HIDDEN + lane], acc);
    emb[(size_t)n * HIDDEN + lane] = fmaxf(acc, 0.0f);
}

// ---------------------------------------------------------------------------
// Flag + compact nodes whose msg is read downstream (~39.3% of nodes).
// ---------------------------------------------------------------------------
__global__ __launch_bounds__(256) void k_setflags(
    const int* __restrict__ post, int* __restrict__ flag,
    int* __restrict__ nodelist, int* __restrict__ inv,
    int* __restrict__ listCnt, int n_posts)
{
    const int p = blockIdx.x * 256 + threadIdx.x;
    if (p >= n_posts) return;
    const int n = post[p];
    if (atomicCAS(&flag[n], 0, 1) == 0) {
        const int i = atomicAdd(listCnt, 1);
        nodelist[i] = n;
        inv[n] = i;
    }
}

// CSR step 1: in-degree count per flagged destination.
__global__ __launch_bounds__(256) void k_count(
    const int* __restrict__ dsts, const int* __restrict__ flag,
    int* __restrict__ count, int n_edges)
{
    const int stride = gridDim.x * 256;
    for (int e = blockIdx.x * 256 + threadIdx.x; e < n_edges; e += stride) {
        const int d = dsts[e];
        if (flag[d]) atomicAdd(&count[d], 1);
    }
}

// ---------------------------------------------------------------------------
// CSR step 2: single-pass exclusive scan (decoupled lookback).
// partials[b] = (status<<30)|value; status: 0 invalid, 1 aggregate, 2 prefix.
// partials pre-zeroed. 98 blocks, all co-resident -> no deadlock.
// ---------------------------------------------------------------------------
__global__ __launch_bounds__(256) void k_scan_lb(
    const int* __restrict__ count, int* __restrict__ row_start,
    unsigned int* __restrict__ partials, int n)
{
    __shared__ int s[256];
    __shared__ int sExc;
    const int b = blockIdx.x, tid = threadIdx.x;
    const int base = b * SCAN_CHUNK + tid * 4;
    int c0 = (base + 0 < n) ? count[base + 0] : 0;
    int c1 = (base + 1 < n) ? count[base + 1] : 0;
    int c2 = (base + 2 < n) ? count[base + 2] : 0;
    int c3 = (base + 3 < n) ? count[base + 3] : 0;
    const int t = c0 + c1 + c2 + c3;
    s[tid] = t;
    __syncthreads();
    #pragma unroll
    for (int off = 1; off < 256; off <<= 1) {
        int v = (tid >= off) ? s[tid - off] : 0;
        __syncthreads();
        s[tid] += v;
        __syncthreads();
    }
    if (tid == 0) {
        const unsigned int total = (unsigned int)s[255];
        if (b == 0) {
            __hip_atomic_store(&partials[0], (2u << 30) | total,
                               __ATOMIC_RELEASE, __HIP_MEMORY_SCOPE_AGENT);
            sExc = 0;
        } else {
            __hip_atomic_store(&partials[b], (1u << 30) | total,
                               __ATOMIC_RELEASE, __HIP_MEMORY_SCOPE_AGENT);
            int exc = 0;
            int j = b - 1;
            while (true) {
                const unsigned int v = __hip_atomic_load(&partials[j],
                    __ATOMIC_ACQUIRE, __HIP_MEMORY_SCOPE_AGENT);
                const unsigned int st = v >> 30;
                if (st == 0u) continue;               // not published yet
                exc += (int)(v & 0x3FFFFFFFu);
                if (st == 2u) break;                  // found a full prefix
                --j;
            }
            __hip_atomic_store(&partials[b], (2u << 30) | (unsigned int)(exc + (int)total),
                               __ATOMIC_RELEASE, __HIP_MEMORY_SCOPE_AGENT);
            sExc = exc;
        }
    }
    __syncthreads();
    int run = sExc + s[tid] - t;
    if (base + 0 < n) row_start[base + 0] = run;           run += c0;
    if (base + 1 < n) row_start[base + 1] = run;           run += c1;
    if (base + 2 < n) row_start[base + 2] = run;           run += c2;
    if (base + 3 < n) row_start[base + 3] = run;
}

// CSR step 3: fill slot lists; atomically consumes row_start -> row_end.
__global__ __launch_bounds__(256) void k_fill(
    const int* __restrict__ srcs, const int* __restrict__ dsts,
    const int* __restrict__ flag, int* __restrict__ row_start,
    int* __restrict__ slots, int n_edges)
{
    const int stride = gridDim.x * 256;
    for (int e = blockIdx.x * 256 + threadIdx.x; e < n_edges; e += stride) {
        const int d = dsts[e];
        if (!flag[d]) continue;
        const int idx = atomicAdd(&row_start[d], 1);
        slots[idx] = srcs[e];
    }
}

// ---------------------------------------------------------------------------
// Fused gather + conv + output head. Wave = 16 compact nodes:
//  (a) per node: sum emb[self]+emb[srcs] (lane=channel, 256 B/row) into a
//      wave-private LDS tile [16][LDSROW];
//  (b) conv via 2 ksteps x 4 ntiles of 16x16x32 bf16 MFMA with hi/lo-split A
//      (fp16-level accuracy);
//  (c) h=relu(.+bc); per-node dot(h,Wo) via intra-quad shfl_xor; sigmoid;
//      one scalar per node -> res_c[i].
// ---------------------------------------------------------------------------
__global__ __launch_bounds__(256) void k_gather_head(
    const int* __restrict__ nodelist, const int* __restrict__ listCnt,
    const int* __restrict__ row_end, const int* __restrict__ count,
    const int* __restrict__ slots, const float* __restrict__ emb,
    const float* __restrict__ Wc, const float* __restrict__ bc,
    const float* __restrict__ Wo, const float* __restrict__ bo,
    float* __restrict__ res_c)
{
    __shared__ float sX[4 * 16 * LDSROW];   // 17.4 KB, wave-private slices
    const int lane = threadIdx.x & 63;
    const int wv   = threadIdx.x >> 6;
    const int r    = lane & 15;
    const int quad = lane >> 4;
    float* X = sX + wv * 16 * LDSROW;

    // B fragments for W_conv: 2 ksteps x 4 ntiles (32 VGPRs), once per wave.
    short8 Wb[2][4];
    #pragma unroll
    for (int ks = 0; ks < 2; ++ks) {
        #pragma unroll
        for (int nt = 0; nt < 4; ++nt) {
            F2B u;
            #pragma unroll
            for (int jj = 0; jj < 4; ++jj) {
                const int k0 = ks * 32 + quad * 8 + 2 * jj;
                const float lo = Wc[(size_t)k0 * HIDDEN + nt * 16 + r];
                const float hi = Wc[(size_t)(k0 + 1) * HIDDEN + nt * 16 + r];
                u.h[jj] = __float22bfloat162_rn(make_float2(lo, hi));
            }
            Wb[ks][nt] = u.s;
        }
    }
    float bias[4], wo[4];
    #pragma unroll
    for (int nt = 0; nt < 4; ++nt) { bias[nt] = bc[nt * 16 + r]; wo[nt] = Wo[nt * 16 + r]; }
    const float bo_s = bo[0];

    const int nc      = listCnt[0];
    const int n_tiles = (nc + 15) / 16;
    const int wid     = (blockIdx.x * 256 + threadIdx.x) >> 6;
    const int nwaves  = gridDim.x * 4;

    for (int tile = wid; tile < n_tiles; tile += nwaves) {
        const int i0 = tile * 16;
        // (a) gather 16 nodes into LDS
        for (int j = 0; j < 16; ++j) {
            const int idx = i0 + j;
            float acc = 0.0f;
            if (idx < nc) {
                const int n    = nodelist[idx];
                const int m    = count[n];
                const int base = row_end[n] - m;
                acc = emb[(size_t)n * HIDDEN + lane];
                int c = 0;
                for (; c + 3 < m; c += 4) {
                    const int s0 = slots[base + c + 0];
                    const int s1 = slots[base + c + 1];
                    const int s2 = slots[base + c + 2];
                    const int s3 = slots[base + c + 3];
                    const float v0 = emb[(size_t)s0 * HIDDEN + lane];
                    const float v1 = emb[(size_t)s1 * HIDDEN + lane];
                    const float v2 = emb[(size_t)s2 * HIDDEN + lane];
                    const float v3 = emb[(size_t)s3 * HIDDEN + lane];
                    acc += (v0 + v1) + (v2 + v3);
                }
                for (; c < m; ++c)
                    acc += emb[(size_t)slots[base + c] * HIDDEN + lane];
            }
            X[j * LDSROW + lane] = acc;     // banks: 2-way, free
        }
        // (b) conv MFMA, hi/lo split A
        floatx4 acc[4] = {};
        #pragma unroll
        for (int ks = 0; ks < 2; ++ks) {
            const float4 f0 = *(const float4*)&X[r * LDSROW + ks * 32 + quad * 8];
            const float4 f1 = *(const float4*)&X[r * LDSROW + ks * 32 + quad * 8 + 4];
            short8 ah, al;
            cvt8_split(f0, f1, ah, al);
            #pragma unroll
            for (int nt = 0; nt < 4; ++nt) {
                acc[nt] = __builtin_amdgcn_mfma_f32_16x16x32_bf16(ah, Wb[ks][nt], acc[nt], 0, 0, 0);
                acc[nt] = __builtin_amdgcn_mfma_f32_16x16x32_bf16(al, Wb[ks][nt], acc[nt], 0, 0, 0);
            }
        }
        // (c) h=relu, dot with Wo across channels (r within quad), sigmoid
        float res[4];
        #pragma unroll
        for (int g = 0; g < 4; ++g) {
            float part = 0.0f;
            #pragma unroll
            for (int nt = 0; nt < 4; ++nt)
                part += fmaxf(acc[nt][g] + bias[nt], 0.0f) * wo[nt];
            part += __shfl_xor(part, 1);
            part += __shfl_xor(part, 2);
            part += __shfl_xor(part, 4);
            part += __shfl_xor(part, 8);
            res[g] = part;
        }
        if (r == 0) {
            #pragma unroll
            for (int g = 0; g < 4; ++g) {
                const int idx = i0 + quad * 4 + g;
                if (idx < nc)
                    res_c[idx] = 1.0f / (1.0f + __expf(-(res[g] + bo_s)));
            }
        }
    }
}

// Final map: out[p] = res_c[inv[post[p]]] (res_c is L2-resident, 157 KB).
__global__ __launch_bounds__(256) void k_out(
    const int* __restrict__ post, const int* __restrict__ inv,
    const float* __restrict__ res_c, float* __restrict__ out, int n_posts)
{
    const int p = blockIdx.x * 256 + threadIdx.x;
    if (p < n_posts) out[p] = res_c[inv[post[p]]];
}

extern "C" void kernel_launch(void* const* d_in, const int* in_sizes, int n_in,
                              void* d_out, int out_size, void* d_ws, size_t ws_size,
                              hipStream_t stream) {
    const float* A    = (const float*)d_in[0];
    const int*   ei   = (const int*)  d_in[1];
    const int*   post = (const int*)  d_in[2];
    const float* We   = (const float*)d_in[3];
    const float* be   = (const float*)d_in[4];
    const float* Wc   = (const float*)d_in[5];
    const float* bc   = (const float*)d_in[6];
    const float* Wo   = (const float*)d_in[7];
    const float* bo   = (const float*)d_in[8];
    float* out = (float*)d_out;

    const int n_nodes = in_sizes[0] / NODE_DIM;   // 100000
    const int n_edges = in_sizes[1] / 2;          // 1200000
    const int n_posts = in_sizes[2];              // 50000

    // ---- workspace layout (every region written before read; ~32 MB) ----
    char* p = (char*)d_ws;
    float* emb      = (float*)p;              p += (size_t)n_nodes * HIDDEN * 4;  // 25.6 MB
    int*   slots    = (int*)p;                p += (size_t)n_edges * 4;           // 4.8 MB
    int*   flag     = (int*)p;                p += (size_t)n_nodes * 4;           // zeroed
    int*   count    = (int*)p;                p += (size_t)n_nodes * 4;           // zeroed
    int*   listCnt  = (int*)p;                p += 256;                           // zeroed
    unsigned int* partials = (unsigned int*)p; p += 512;                          // zeroed
    int*   row_start= (int*)p;                p += (size_t)n_nodes * 4;
    int*   nodelist = (int*)p;                p += (size_t)n_nodes * 4;
    int*   inv      = (int*)p;                p += (size_t)n_nodes * 4;
    float* res_c    = (float*)p;              p += (size_t)n_posts * 4;

    const int* srcs = ei;
    const int* dsts = ei + n_edges;
    const int nb = (n_nodes + SCAN_CHUNK - 1) / SCAN_CHUNK;   // 98
    const int n_tiles = n_nodes / 16;
    const int rem     = n_nodes - n_tiles * 16;

    // flag, count, listCnt, partials are contiguous -> single memset
    hipMemsetAsync(flag, 0, (size_t)n_nodes * 8 + 256 + 512, stream);
    k_setflags<<<(n_posts + 255) / 256, 256, 0, stream>>>(post, flag, nodelist, inv, listCnt, n_posts);
    k_encode_mfma<<<(n_tiles + 3) / 4, 256, 0, stream>>>(A, We, be, emb, n_tiles);
    if (rem > 0)
        k_encode_tail<<<rem, 64, 0, stream>>>(A, We, be, emb, n_tiles * 16);
    k_count<<<2048, 256, 0, stream>>>(dsts, flag, count, n_edges);
    k_scan_lb<<<nb, 256, 0, stream>>>(count, row_start, partials, n_nodes);
    k_fill<<<2048, 256, 0, stream>>>(srcs, dsts, flag, row_start, slots, n_edges);
    k_gather_head<<<1024, 256, 0, stream>>>(nodelist, listCnt, row_start, count, slots,
                                            emb, Wc, bc, Wo, bo, res_c);
    k_out<<<(n_posts + 255) / 256, 256, 0, stream>>>(post, inv, res_c, out, n_posts);
}

// Round 7
// 229.389 us; speedup vs baseline: 1.1246x; 1.1246x over previous
//
#include <hip/hip_runtime.h>
#include <hip/hip_bf16.h>
#include <math.h>

// Problem shape (SimpleGCN):
//   node_features [N=100000, 128] f32
//   edge_index    [2, E=1200000] i32   (row 0 = src, row 1 = dst)
//   post_mask     [P=50000] i32
//   W_enc [128,64] b_enc [64]  W_conv [64,64] b_conv [64]  W_out [64,1] b_out [1]
// out[p] = sigmoid( relu( (emb + segsum(emb[src]->dst))[post[p]] @ Wc + bc ) @ Wo + bo )
//
// Round-6 lesson: fusing gather+head into 16-node tiles cut wave count to
// ~2456 and serialized the gather (63 us, all pipes <22%). Unfused again:
// gather = wave/node with 4 concurrent float4 row-slices (8 lines in flight),
// head = separate MFMA kernel on the compacted msg_c (coalesced, ~2456 waves).

#define HIDDEN 64
#define NODE_DIM 128
#define SCAN_CHUNK 1024   // 256 threads x 4 elements per scan block

typedef __attribute__((ext_vector_type(8))) short short8;   // 8 bf16 (4 VGPR)
typedef __attribute__((ext_vector_type(4))) float floatx4;  // mfma C/D frag

union F2B { short8 s; __hip_bfloat162 h[4]; };

__device__ inline short8 cvt8(const float4& p, const float4& q) {
    F2B u;
    u.h[0] = __float22bfloat162_rn(make_float2(p.x, p.y));
    u.h[1] = __float22bfloat162_rn(make_float2(p.z, p.w));
    u.h[2] = __float22bfloat162_rn(make_float2(q.x, q.y));
    u.h[3] = __float22bfloat162_rn(make_float2(q.z, q.w));
    return u.s;
}

// hi/lo bf16 split of 8 floats: hi = bf16(x), lo = bf16(x - float(hi)).
__device__ inline void cvt8_split(const float4& p, const float4& q,
                                  short8& hi, short8& lo) {
    const float f[8] = {p.x, p.y, p.z, p.w, q.x, q.y, q.z, q.w};
    F2B uh, ul;
    #pragma unroll
    for (int jj = 0; jj < 4; ++jj) {
        const float2 v = make_float2(f[2 * jj], f[2 * jj + 1]);
        const __hip_bfloat162 h = __float22bfloat162_rn(v);
        const float2 hv = __bfloat1622float2(h);
        ul.h[jj] = __float22bfloat162_rn(make_float2(v.x - hv.x, v.y - hv.y));
        uh.h[jj] = h;
    }
    hi = uh.s; lo = ul.s;
}

__device__ inline void add4(float4& a, const float4& b) {
    a.x += b.x; a.y += b.y; a.z += b.z; a.w += b.w;
}

// ---------------------------------------------------------------------------
// Stage 1 (MFMA): emb = relu(A @ W_enc + b_enc).
// Wave = 16-node M-tile: 4 ksteps x 4 ntiles of 16x16x32 bf16 mfma.
// ---------------------------------------------------------------------------
__global__ __launch_bounds__(256) void k_encode_mfma(
    const float* __restrict__ A, const float* __restrict__ We,
    const float* __restrict__ be, float* __restrict__ emb, int n_tiles)
{
    const int lane = threadIdx.x & 63;
    const int r    = lane & 15;
    const int quad = lane >> 4;

    short8 Wb[4][4];   // [kstep][ntile], built once per wave
    #pragma unroll
    for (int ks = 0; ks < 4; ++ks) {
        #pragma unroll
        for (int nt = 0; nt < 4; ++nt) {
            F2B u;
            #pragma unroll
            for (int jj = 0; jj < 4; ++jj) {
                const int k0 = ks * 32 + quad * 8 + 2 * jj;
                const float lo = We[(size_t)k0 * HIDDEN + nt * 16 + r];
                const float hi = We[(size_t)(k0 + 1) * HIDDEN + nt * 16 + r];
                u.h[jj] = __float22bfloat162_rn(make_float2(lo, hi));
            }
            Wb[ks][nt] = u.s;
        }
    }
    float bias[4];
    #pragma unroll
    for (int nt = 0; nt < 4; ++nt) bias[nt] = be[nt * 16 + r];

    const int wid    = (blockIdx.x * 256 + threadIdx.x) >> 6;
    const int nwaves = gridDim.x * 4;
    for (int t = wid; t < n_tiles; t += nwaves) {
        const float* Arow = A + (size_t)t * 16 * NODE_DIM + (size_t)r * NODE_DIM + quad * 8;
        float4 a[4][2];
        #pragma unroll
        for (int ks = 0; ks < 4; ++ks) {
            a[ks][0] = *(const float4*)(Arow + ks * 32);
            a[ks][1] = *(const float4*)(Arow + ks * 32 + 4);
        }
        floatx4 acc[4] = {};
        #pragma unroll
        for (int ks = 0; ks < 4; ++ks) {
            const short8 af = cvt8(a[ks][0], a[ks][1]);
            #pragma unroll
            for (int nt = 0; nt < 4; ++nt)
                acc[nt] = __builtin_amdgcn_mfma_f32_16x16x32_bf16(af, Wb[ks][nt], acc[nt], 0, 0, 0);
        }
        #pragma unroll
        for (int nt = 0; nt < 4; ++nt) {
            #pragma unroll
            for (int g = 0; g < 4; ++g) {
                const int node = t * 16 + quad * 4 + g;
                const float h = fmaxf(acc[nt][g] + bias[nt], 0.0f);
                emb[(size_t)node * HIDDEN + nt * 16 + r] = h;
            }
        }
    }
}

// Tail nodes (n_nodes % 16) — plain vector path (not launched for 100000).
__global__ __launch_bounds__(64) void k_encode_tail(
    const float* __restrict__ A, const float* __restrict__ We,
    const float* __restrict__ be, float* __restrict__ emb, int base)
{
    const int lane = threadIdx.x;
    const int n = base + blockIdx.x;
    const float* row = A + (size_t)n * NODE_DIM;
    float acc = be[lane];
    for (int k = 0; k < NODE_DIM; ++k)
        acc = fmaf(row[k], We[(size_t)k * HIDDEN + lane], acc);
    emb[(size_t)n * HIDDEN + lane] = fmaxf(acc, 0.0f);
}

// ---------------------------------------------------------------------------
// Flag + compact nodes whose msg is read downstream (~39.3% of nodes).
// ---------------------------------------------------------------------------
__global__ __launch_bounds__(256) void k_setflags(
    const int* __restrict__ post, int* __restrict__ flag,
    int* __restrict__ nodelist, int* __restrict__ inv,
    int* __restrict__ listCnt, int n_posts)
{
    const int p = blockIdx.x * 256 + threadIdx.x;
    if (p >= n_posts) return;
    const int n = post[p];
    if (atomicCAS(&flag[n], 0, 1) == 0) {
        const int i = atomicAdd(listCnt, 1);
        nodelist[i] = n;
        inv[n] = i;
    }
}

// CSR step 1: in-degree count per flagged destination.
__global__ __launch_bounds__(256) void k_count(
    const int* __restrict__ dsts, const int* __restrict__ flag,
    int* __restrict__ count, int n_edges)
{
    const int stride = gridDim.x * 256;
    for (int e = blockIdx.x * 256 + threadIdx.x; e < n_edges; e += stride) {
        const int d = dsts[e];
        if (flag[d]) atomicAdd(&count[d], 1);
    }
}

// ---------------------------------------------------------------------------
// CSR step 2: single-pass exclusive scan (decoupled lookback).
// ---------------------------------------------------------------------------
__global__ __launch_bounds__(256) void k_scan_lb(
    const int* __restrict__ count, int* __restrict__ row_start,
    unsigned int* __restrict__ partials, int n)
{
    __shared__ int s[256];
    __shared__ int sExc;
    const int b = blockIdx.x, tid = threadIdx.x;
    const int base = b * SCAN_CHUNK + tid * 4;
    int c0 = (base + 0 < n) ? count[base + 0] : 0;
    int c1 = (base + 1 < n) ? count[base + 1] : 0;
    int c2 = (base + 2 < n) ? count[base + 2] : 0;
    int c3 = (base + 3 < n) ? count[base + 3] : 0;
    const int t = c0 + c1 + c2 + c3;
    s[tid] = t;
    __syncthreads();
    #pragma unroll
    for (int off = 1; off < 256; off <<= 1) {
        int v = (tid >= off) ? s[tid - off] : 0;
        __syncthreads();
        s[tid] += v;
        __syncthreads();
    }
    if (tid == 0) {
        const unsigned int total = (unsigned int)s[255];
        if (b == 0) {
            __hip_atomic_store(&partials[0], (2u << 30) | total,
                               __ATOMIC_RELEASE, __HIP_MEMORY_SCOPE_AGENT);
            sExc = 0;
        } else {
            __hip_atomic_store(&partials[b], (1u << 30) | total,
                               __ATOMIC_RELEASE, __HIP_MEMORY_SCOPE_AGENT);
            int exc = 0;
            int j = b - 1;
            while (true) {
                const unsigned int v = __hip_atomic_load(&partials[j],
                    __ATOMIC_ACQUIRE, __HIP_MEMORY_SCOPE_AGENT);
                const unsigned int st = v >> 30;
                if (st == 0u) continue;
                exc += (int)(v & 0x3FFFFFFFu);
                if (st == 2u) break;
                --j;
            }
            __hip_atomic_store(&partials[b], (2u << 30) | (unsigned int)(exc + (int)total),
                               __ATOMIC_RELEASE, __HIP_MEMORY_SCOPE_AGENT);
            sExc = exc;
        }
    }
    __syncthreads();
    int run = sExc + s[tid] - t;
    if (base + 0 < n) row_start[base + 0] = run;           run += c0;
    if (base + 1 < n) row_start[base + 1] = run;           run += c1;
    if (base + 2 < n) row_start[base + 2] = run;           run += c2;
    if (base + 3 < n) row_start[base + 3] = run;
}

// CSR step 3: fill slot lists; atomically consumes row_start -> row_end.
__global__ __launch_bounds__(256) void k_fill(
    const int* __restrict__ srcs, const int* __restrict__ dsts,
    const int* __restrict__ flag, int* __restrict__ row_start,
    int* __restrict__ slots, int n_edges)
{
    const int stride = gridDim.x * 256;
    for (int e = blockIdx.x * 256 + threadIdx.x; e < n_edges; e += stride) {
        const int d = dsts[e];
        if (!flag[d]) continue;
        const int idx = atomicAdd(&row_start[d], 1);
        slots[idx] = srcs[e];
    }
}

// ---------------------------------------------------------------------------
// Gather v2: one wave per compact node. 4 groups x 16 lanes; each group pulls
// a full 256 B emb row (float4/lane) of a DIFFERENT edge; groups stride the
// edge list by 4, 2-deep unroll -> up to 8 rows in flight per wave.
// Cross-group sum via 2 rounds of shfl_xor; one compact row written.
// ---------------------------------------------------------------------------
__global__ __launch_bounds__(256) void k_gather(
    const int* __restrict__ nodelist, const int* __restrict__ listCnt,
    const int* __restrict__ row_end, const int* __restrict__ count,
    const int* __restrict__ slots, const float* __restrict__ emb,
    float* __restrict__ msg_c)
{
    const int lane = threadIdx.x & 63;
    const int j    = lane & 15;          // float4 index within row
    const int g    = lane >> 4;          // edge group
    const int gw   = (blockIdx.x * 256 + threadIdx.x) >> 6;
    const int nw   = gridDim.x * 4;
    const int nc   = listCnt[0];
    const float4* __restrict__ emb4 = (const float4*)emb;

    for (int i = gw; i < nc; i += nw) {
        const int n    = nodelist[i];
        const int m    = count[n];
        const int base = row_end[n] - m;

        float4 acc = make_float4(0.f, 0.f, 0.f, 0.f);
        if (g == 0) acc = emb4[(size_t)n * 16 + j];          // self row
        int c = g;
        for (; c + 4 < m; c += 8) {                           // 2 rows in flight/group
            const int s0 = slots[base + c];
            const int s1 = slots[base + c + 4];
            const float4 v0 = emb4[(size_t)s0 * 16 + j];
            const float4 v1 = emb4[(size_t)s1 * 16 + j];
            add4(acc, v0); add4(acc, v1);
        }
        for (; c < m; c += 4) {
            const int s0 = slots[base + c];
            const float4 v0 = emb4[(size_t)s0 * 16 + j];
            add4(acc, v0);
        }
        // sum the 4 groups (lanes with equal j)
        #pragma unroll
        for (int off = 16; off < 64; off <<= 1) {
            acc.x += __shfl_xor(acc.x, off);
            acc.y += __shfl_xor(acc.y, off);
            acc.z += __shfl_xor(acc.z, off);
            acc.w += __shfl_xor(acc.w, off);
        }
        if (g == 0)
            ((float4*)msg_c)[(size_t)i * 16 + j] = acc;       // 256 B row write
    }
}

// ---------------------------------------------------------------------------
// Head (MFMA): wave per 16 compact rows of msg_c (coalesced, no indirection).
// h = relu(msg @ Wc + bc) via hi/lo-split bf16 MFMA; res = sigmoid(h.Wo + bo).
// ---------------------------------------------------------------------------
__global__ __launch_bounds__(256) void k_head_mfma(
    const int* __restrict__ listCnt, const float* __restrict__ msg_c,
    const float* __restrict__ Wc, const float* __restrict__ bc,
    const float* __restrict__ Wo, const float* __restrict__ bo,
    float* __restrict__ res_c)
{
    const int lane = threadIdx.x & 63;
    const int r    = lane & 15;
    const int quad = lane >> 4;

    short8 Wb[2][4];   // W_conv fragments, once per wave
    #pragma unroll
    for (int ks = 0; ks < 2; ++ks) {
        #pragma unroll
        for (int nt = 0; nt < 4; ++nt) {
            F2B u;
            #pragma unroll
            for (int jj = 0; jj < 4; ++jj) {
                const int k0 = ks * 32 + quad * 8 + 2 * jj;
                const float lo = Wc[(size_t)k0 * HIDDEN + nt * 16 + r];
                const float hi = Wc[(size_t)(k0 + 1) * HIDDEN + nt * 16 + r];
                u.h[jj] = __float22bfloat162_rn(make_float2(lo, hi));
            }
            Wb[ks][nt] = u.s;
        }
    }
    float bias[4], wo[4];
    #pragma unroll
    for (int nt = 0; nt < 4; ++nt) { bias[nt] = bc[nt * 16 + r]; wo[nt] = Wo[nt * 16 + r]; }
    const float bo_s = bo[0];

    const int nc      = listCnt[0];
    const int n_tiles = (nc + 15) / 16;
    const int wid     = (blockIdx.x * 256 + threadIdx.x) >> 6;
    const int nwaves  = gridDim.x * 4;

    for (int tile = wid; tile < n_tiles; tile += nwaves) {
        const int i0  = tile * 16;
        const int row = i0 + r;
        floatx4 acc[4] = {};
        #pragma unroll
        for (int ks = 0; ks < 2; ++ks) {
            float4 f0 = make_float4(0.f, 0.f, 0.f, 0.f), f1 = f0;
            if (row < nc) {
                const float* src = msg_c + (size_t)row * HIDDEN + ks * 32 + quad * 8;
                f0 = *(const float4*)src;
                f1 = *(const float4*)(src + 4);
            }
            short8 ah, al;
            cvt8_split(f0, f1, ah, al);
            #pragma unroll
            for (int nt = 0; nt < 4; ++nt) {
                acc[nt] = __builtin_amdgcn_mfma_f32_16x16x32_bf16(ah, Wb[ks][nt], acc[nt], 0, 0, 0);
                acc[nt] = __builtin_amdgcn_mfma_f32_16x16x32_bf16(al, Wb[ks][nt], acc[nt], 0, 0, 0);
            }
        }
        float res[4];
        #pragma unroll
        for (int gg = 0; gg < 4; ++gg) {
            float part = 0.0f;
            #pragma unroll
            for (int nt = 0; nt < 4; ++nt)
                part += fmaxf(acc[nt][gg] + bias[nt], 0.0f) * wo[nt];
            part += __shfl_xor(part, 1);
            part += __shfl_xor(part, 2);
            part += __shfl_xor(part, 4);
            part += __shfl_xor(part, 8);
            res[gg] = part;
        }
        if (r == 0) {
            #pragma unroll
            for (int gg = 0; gg < 4; ++gg) {
                const int idx = i0 + quad * 4 + gg;
                if (idx < nc)
                    res_c[idx] = 1.0f / (1.0f + __expf(-(res[gg] + bo_s)));
            }
        }
    }
}

// Final map: out[p] = res_c[inv[post[p]]] (res_c is L2-resident, 157 KB).
__global__ __launch_bounds__(256) void k_out(
    const int* __restrict__ post, const int* __restrict__ inv,
    const float* __restrict__ res_c, float* __restrict__ out, int n_posts)
{
    const int p = blockIdx.x * 256 + threadIdx.x;
    if (p < n_posts) out[p] = res_c[inv[post[p]]];
}

extern "C" void kernel_launch(void* const* d_in, const int* in_sizes, int n_in,
                              void* d_out, int out_size, void* d_ws, size_t ws_size,
                              hipStream_t stream) {
    const float* A    = (const float*)d_in[0];
    const int*   ei   = (const int*)  d_in[1];
    const int*   post = (const int*)  d_in[2];
    const float* We   = (const float*)d_in[3];
    const float* be   = (const float*)d_in[4];
    const float* Wc   = (const float*)d_in[5];
    const float* bc   = (const float*)d_in[6];
    const float* Wo   = (const float*)d_in[7];
    const float* bo   = (const float*)d_in[8];
    float* out = (float*)d_out;

    const int n_nodes = in_sizes[0] / NODE_DIM;   // 100000
    const int n_edges = in_sizes[1] / 2;          // 1200000
    const int n_posts = in_sizes[2];              // 50000

    // ---- workspace layout (every region written before read; ~45 MB) ----
    char* p = (char*)d_ws;
    float* emb      = (float*)p;              p += (size_t)n_nodes * HIDDEN * 4;  // 25.6 MB
    float* msg_c    = (float*)p;              p += (size_t)n_posts * HIDDEN * 4;  // 12.8 MB
    int*   slots    = (int*)p;                p += (size_t)n_edges * 4;           // 4.8 MB
    int*   flag     = (int*)p;                p += (size_t)n_nodes * 4;           // zeroed
    int*   count    = (int*)p;                p += (size_t)n_nodes * 4;           // zeroed
    int*   listCnt  = (int*)p;                p += 256;                           // zeroed
    unsigned int* partials = (unsigned int*)p; p += 512;                          // zeroed
    int*   row_start= (int*)p;                p += (size_t)n_nodes * 4;
    int*   nodelist = (int*)p;                p += (size_t)n_nodes * 4;
    int*   inv      = (int*)p;                p += (size_t)n_nodes * 4;
    float* res_c    = (float*)p;              p += (size_t)n_posts * 4;

    const int* srcs = ei;
    const int* dsts = ei + n_edges;
    const int nb = (n_nodes + SCAN_CHUNK - 1) / SCAN_CHUNK;   // 98
    const int n_tiles = n_nodes / 16;
    const int rem     = n_nodes - n_tiles * 16;

    // flag, count, listCnt, partials are contiguous -> single memset
    hipMemsetAsync(flag, 0, (size_t)n_nodes * 8 + 256 + 512, stream);
    k_setflags<<<(n_posts + 255) / 256, 256, 0, stream>>>(post, flag, nodelist, inv, listCnt, n_posts);
    k_encode_mfma<<<(n_tiles + 3) / 4, 256, 0, stream>>>(A, We, be, emb, n_tiles);
    if (rem > 0)
        k_encode_tail<<<rem, 64, 0, stream>>>(A, We, be, emb, n_tiles * 16);
    k_count<<<2048, 256, 0, stream>>>(dsts, flag, count, n_edges);
    k_scan_lb<<<nb, 256, 0, stream>>>(count, row_start, partials, n_nodes);
    k_fill<<<2048, 256, 0, stream>>>(srcs, dsts, flag, row_start, slots, n_edges);
    k_gather<<<8192, 256, 0, stream>>>(nodelist, listCnt, row_start, count, slots, emb, msg_c);
    k_head_mfma<<<1024, 256, 0, stream>>>(listCnt, msg_c, Wc, bc, Wo, bo, res_c);
    k_out<<<(n_posts + 255) / 256, 256, 0, stream>>>(post, inv, res_c, out, n_posts);
}

// Round 8
// 223.442 us; speedup vs baseline: 1.1546x; 1.0266x over previous
//
#include <hip/hip_runtime.h>
#include <hip/hip_bf16.h>
#include <math.h>

// Problem shape (SimpleGCN):
//   node_features [N=100000, 128] f32
//   edge_index    [2, E=1200000] i32   (row 0 = src, row 1 = dst)
//   post_mask     [P=50000] i32
//   W_enc [128,64] b_enc [64]  W_conv [64,64] b_conv [64]  W_out [64,1] b_out [1]
// out[p] = sigmoid( relu( (emb + segsum(emb[src]->dst))[post[p]] @ Wc + bc ) @ Wo + bo )
//
// Round-7 state: structure sound (encode MFMA -> CSR build -> gather -> head
// MFMA), every kernel < 41 us. This round cuts BYTES: emb stored bf16 (halves
// gather's random-row traffic + encode writes), gather uses 8 groups x 8 lanes
// (one 128 B row per group, 16 rows in flight), and count/fill use an
// L1-resident 12.5 KB bitmask instead of random 400 KB int-flag lookups.

#define HIDDEN 64
#define NODE_DIM 128
#define SCAN_CHUNK 1024   // 256 threads x 4 elements per scan block

typedef __attribute__((ext_vector_type(8))) short short8;   // 8 bf16 (4 VGPR)
typedef __attribute__((ext_vector_type(4))) float floatx4;  // mfma C/D frag

union F2B { short8 s; __hip_bfloat162 h[4]; };

__device__ inline short8 cvt8(const float4& p, const float4& q) {
    F2B u;
    u.h[0] = __float22bfloat162_rn(make_float2(p.x, p.y));
    u.h[1] = __float22bfloat162_rn(make_float2(p.z, p.w));
    u.h[2] = __float22bfloat162_rn(make_float2(q.x, q.y));
    u.h[3] = __float22bfloat162_rn(make_float2(q.z, q.w));
    return u.s;
}

// hi/lo bf16 split of 8 floats: hi = bf16(x), lo = bf16(x - float(hi)).
__device__ inline void cvt8_split(const float4& p, const float4& q,
                                  short8& hi, short8& lo) {
    const float f[8] = {p.x, p.y, p.z, p.w, q.x, q.y, q.z, q.w};
    F2B uh, ul;
    #pragma unroll
    for (int jj = 0; jj < 4; ++jj) {
        const float2 v = make_float2(f[2 * jj], f[2 * jj + 1]);
        const __hip_bfloat162 h = __float22bfloat162_rn(v);
        const float2 hv = __bfloat1622float2(h);
        ul.h[jj] = __float22bfloat162_rn(make_float2(v.x - hv.x, v.y - hv.y));
        uh.h[jj] = h;
    }
    hi = uh.s; lo = ul.s;
}

// ---------------------------------------------------------------------------
// Stage 1 (MFMA): emb = relu(A @ W_enc + b_enc), stored BF16 (128 B rows).
// Wave = 16-node M-tile: 4 ksteps x 4 ntiles of 16x16x32 bf16 mfma.
// ---------------------------------------------------------------------------
__global__ __launch_bounds__(256) void k_encode_mfma(
    const float* __restrict__ A, const float* __restrict__ We,
    const float* __restrict__ be, __hip_bfloat16* __restrict__ emb16, int n_tiles)
{
    const int lane = threadIdx.x & 63;
    const int r    = lane & 15;
    const int quad = lane >> 4;

    short8 Wb[4][4];   // [kstep][ntile], built once per wave
    #pragma unroll
    for (int ks = 0; ks < 4; ++ks) {
        #pragma unroll
        for (int nt = 0; nt < 4; ++nt) {
            F2B u;
            #pragma unroll
            for (int jj = 0; jj < 4; ++jj) {
                const int k0 = ks * 32 + quad * 8 + 2 * jj;
                const float lo = We[(size_t)k0 * HIDDEN + nt * 16 + r];
                const float hi = We[(size_t)(k0 + 1) * HIDDEN + nt * 16 + r];
                u.h[jj] = __float22bfloat162_rn(make_float2(lo, hi));
            }
            Wb[ks][nt] = u.s;
        }
    }
    float bias[4];
    #pragma unroll
    for (int nt = 0; nt < 4; ++nt) bias[nt] = be[nt * 16 + r];

    const int wid    = (blockIdx.x * 256 + threadIdx.x) >> 6;
    const int nwaves = gridDim.x * 4;
    for (int t = wid; t < n_tiles; t += nwaves) {
        const float* Arow = A + (size_t)t * 16 * NODE_DIM + (size_t)r * NODE_DIM + quad * 8;
        float4 a[4][2];
        #pragma unroll
        for (int ks = 0; ks < 4; ++ks) {
            a[ks][0] = *(const float4*)(Arow + ks * 32);
            a[ks][1] = *(const float4*)(Arow + ks * 32 + 4);
        }
        floatx4 acc[4] = {};
        #pragma unroll
        for (int ks = 0; ks < 4; ++ks) {
            const short8 af = cvt8(a[ks][0], a[ks][1]);
            #pragma unroll
            for (int nt = 0; nt < 4; ++nt)
                acc[nt] = __builtin_amdgcn_mfma_f32_16x16x32_bf16(af, Wb[ks][nt], acc[nt], 0, 0, 0);
        }
        #pragma unroll
        for (int nt = 0; nt < 4; ++nt) {
            #pragma unroll
            for (int g = 0; g < 4; ++g) {
                const int node = t * 16 + quad * 4 + g;
                const float h = fmaxf(acc[nt][g] + bias[nt], 0.0f);
                emb16[(size_t)node * HIDDEN + nt * 16 + r] = __float2bfloat16(h);
            }
        }
    }
}

// Tail nodes (n_nodes % 16) — plain vector path (not launched for 100000).
__global__ __launch_bounds__(64) void k_encode_tail(
    const float* __restrict__ A, const float* __restrict__ We,
    const float* __restrict__ be, __hip_bfloat16* __restrict__ emb16, int base)
{
    const int lane = threadIdx.x;
    const int n = base + blockIdx.x;
    const float* row = A + (size_t)n * NODE_DIM;
    float acc = be[lane];
    for (int k = 0; k < NODE_DIM; ++k)
        acc = fmaf(row[k], We[(size_t)k * HIDDEN + lane], acc);
    emb16[(size_t)n * HIDDEN + lane] = __float2bfloat16(fmaxf(acc, 0.0f));
}

// ---------------------------------------------------------------------------
// Flag (bitmask, L1-resident) + compact nodes whose msg is read (~39.3%).
// ---------------------------------------------------------------------------
__global__ __launch_bounds__(256) void k_setflags(
    const int* __restrict__ post, int* __restrict__ flag,
    unsigned int* __restrict__ bits,
    int* __restrict__ nodelist, int* __restrict__ inv,
    int* __restrict__ listCnt, int n_posts)
{
    const int p = blockIdx.x * 256 + threadIdx.x;
    if (p >= n_posts) return;
    const int n = post[p];
    atomicOr(&bits[n >> 5], 1u << (n & 31));
    if (atomicCAS(&flag[n], 0, 1) == 0) {
        const int i = atomicAdd(listCnt, 1);
        nodelist[i] = n;
        inv[n] = i;
    }
}

// CSR step 1: in-degree count per flagged destination (bitmask check = L1 hit).
__global__ __launch_bounds__(256) void k_count(
    const int* __restrict__ dsts, const unsigned int* __restrict__ bits,
    int* __restrict__ count, int n_edges)
{
    const int stride = gridDim.x * 256;
    for (int e = blockIdx.x * 256 + threadIdx.x; e < n_edges; e += stride) {
        const int d = dsts[e];
        if ((bits[d >> 5] >> (d & 31)) & 1u) atomicAdd(&count[d], 1);
    }
}

// ---------------------------------------------------------------------------
// CSR step 2: single-pass exclusive scan (decoupled lookback).
// ---------------------------------------------------------------------------
__global__ __launch_bounds__(256) void k_scan_lb(
    const int* __restrict__ count, int* __restrict__ row_start,
    unsigned int* __restrict__ partials, int n)
{
    __shared__ int s[256];
    __shared__ int sExc;
    const int b = blockIdx.x, tid = threadIdx.x;
    const int base = b * SCAN_CHUNK + tid * 4;
    int c0 = (base + 0 < n) ? count[base + 0] : 0;
    int c1 = (base + 1 < n) ? count[base + 1] : 0;
    int c2 = (base + 2 < n) ? count[base + 2] : 0;
    int c3 = (base + 3 < n) ? count[base + 3] : 0;
    const int t = c0 + c1 + c2 + c3;
    s[tid] = t;
    __syncthreads();
    #pragma unroll
    for (int off = 1; off < 256; off <<= 1) {
        int v = (tid >= off) ? s[tid - off] : 0;
        __syncthreads();
        s[tid] += v;
        __syncthreads();
    }
    if (tid == 0) {
        const unsigned int total = (unsigned int)s[255];
        if (b == 0) {
            __hip_atomic_store(&partials[0], (2u << 30) | total,
                               __ATOMIC_RELEASE, __HIP_MEMORY_SCOPE_AGENT);
            sExc = 0;
        } else {
            __hip_atomic_store(&partials[b], (1u << 30) | total,
                               __ATOMIC_RELEASE, __HIP_MEMORY_SCOPE_AGENT);
            int exc = 0;
            int j = b - 1;
            while (true) {
                const unsigned int v = __hip_atomic_load(&partials[j],
                    __ATOMIC_ACQUIRE, __HIP_MEMORY_SCOPE_AGENT);
                const unsigned int st = v >> 30;
                if (st == 0u) continue;
                exc += (int)(v & 0x3FFFFFFFu);
                if (st == 2u) break;
                --j;
            }
            __hip_atomic_store(&partials[b], (2u << 30) | (unsigned int)(exc + (int)total),
                               __ATOMIC_RELEASE, __HIP_MEMORY_SCOPE_AGENT);
            sExc = exc;
        }
    }
    __syncthreads();
    int run = sExc + s[tid] - t;
    if (base + 0 < n) row_start[base + 0] = run;           run += c0;
    if (base + 1 < n) row_start[base + 1] = run;           run += c1;
    if (base + 2 < n) row_start[base + 2] = run;           run += c2;
    if (base + 3 < n) row_start[base + 3] = run;
}

// CSR step 3: fill slot lists; atomically consumes row_start -> row_end.
__global__ __launch_bounds__(256) void k_fill(
    const int* __restrict__ srcs, const int* __restrict__ dsts,
    const unsigned int* __restrict__ bits, int* __restrict__ row_start,
    int* __restrict__ slots, int n_edges)
{
    const int stride = gridDim.x * 256;
    for (int e = blockIdx.x * 256 + threadIdx.x; e < n_edges; e += stride) {
        const int d = dsts[e];
        if (!((bits[d >> 5] >> (d & 31)) & 1u)) continue;
        const int idx = atomicAdd(&row_start[d], 1);
        slots[idx] = srcs[e];
    }
}

// ---------------------------------------------------------------------------
// Gather v3 (bf16 rows): one wave per compact node. 8 groups x 8 lanes; each
// group pulls one full 128 B bf16 row (short8/lane); groups stride the edge
// list by 8, 2-deep unroll -> up to 16 rows in flight. f32 accumulate;
// 3-round shfl_xor cross-group reduce; group 0 writes the f32 msg_c row.
// ---------------------------------------------------------------------------
__global__ __launch_bounds__(256) void k_gather(
    const int* __restrict__ nodelist, const int* __restrict__ listCnt,
    const int* __restrict__ row_end, const int* __restrict__ count,
    const int* __restrict__ slots, const __hip_bfloat16* __restrict__ emb16,
    float* __restrict__ msg_c)
{
    const int lane = threadIdx.x & 63;
    const int j    = lane & 7;           // short8 slice within 128 B row
    const int g    = lane >> 3;          // edge group (0..7)
    const int gw   = (blockIdx.x * 256 + threadIdx.x) >> 6;
    const int nw   = gridDim.x * 4;
    const int nc   = listCnt[0];

    for (int i = gw; i < nc; i += nw) {
        const int n    = nodelist[i];
        const int m    = count[n];
        const int base = row_end[n] - m;

        float2 a0 = {0.f, 0.f}, a1 = {0.f, 0.f}, a2 = {0.f, 0.f}, a3 = {0.f, 0.f};
        #define ACC8(v)  do { F2B u; u.s = (v); float2 t;                       \
            t = __bfloat1622float2(u.h[0]); a0.x += t.x; a0.y += t.y;           \
            t = __bfloat1622float2(u.h[1]); a1.x += t.x; a1.y += t.y;           \
            t = __bfloat1622float2(u.h[2]); a2.x += t.x; a2.y += t.y;           \
            t = __bfloat1622float2(u.h[3]); a3.x += t.x; a3.y += t.y; } while (0)

        if (g == 0) {
            const short8 v = *(const short8*)(emb16 + (size_t)n * HIDDEN + j * 8);
            ACC8(v);
        }
        int c = g;
        for (; c + 8 < m; c += 16) {                 // 2 rows in flight per group
            const int s0 = slots[base + c];
            const int s1 = slots[base + c + 8];
            const short8 v0 = *(const short8*)(emb16 + (size_t)s0 * HIDDEN + j * 8);
            const short8 v1 = *(const short8*)(emb16 + (size_t)s1 * HIDDEN + j * 8);
            ACC8(v0); ACC8(v1);
        }
        for (; c < m; c += 8) {
            const int s0 = slots[base + c];
            const short8 v0 = *(const short8*)(emb16 + (size_t)s0 * HIDDEN + j * 8);
            ACC8(v0);
        }
        #undef ACC8

        // reduce the 8 groups (lanes with equal j)
        #pragma unroll
        for (int off = 8; off < 64; off <<= 1) {
            a0.x += __shfl_xor(a0.x, off); a0.y += __shfl_xor(a0.y, off);
            a1.x += __shfl_xor(a1.x, off); a1.y += __shfl_xor(a1.y, off);
            a2.x += __shfl_xor(a2.x, off); a2.y += __shfl_xor(a2.y, off);
            a3.x += __shfl_xor(a3.x, off); a3.y += __shfl_xor(a3.y, off);
        }
        if (g == 0) {
            float4* dst = (float4*)(msg_c + (size_t)i * HIDDEN + j * 8);
            dst[0] = make_float4(a0.x, a0.y, a1.x, a1.y);
            dst[1] = make_float4(a2.x, a2.y, a3.x, a3.y);
        }
    }
}

// ---------------------------------------------------------------------------
// Head (MFMA): wave per 16 compact rows of msg_c (coalesced, no indirection).
// h = relu(msg @ Wc + bc) via hi/lo-split bf16 MFMA; res = sigmoid(h.Wo + bo).
// ---------------------------------------------------------------------------
__global__ __launch_bounds__(256) void k_head_mfma(
    const int* __restrict__ listCnt, const float* __restrict__ msg_c,
    const float* __restrict__ Wc, const float* __restrict__ bc,
    const float* __restrict__ Wo, const float* __restrict__ bo,
    float* __restrict__ res_c)
{
    const int lane = threadIdx.x & 63;
    const int r    = lane & 15;
    const int quad = lane >> 4;

    short8 Wb[2][4];   // W_conv fragments, once per wave
    #pragma unroll
    for (int ks = 0; ks < 2; ++ks) {
        #pragma unroll
        for (int nt = 0; nt < 4; ++nt) {
            F2B u;
            #pragma unroll
            for (int jj = 0; jj < 4; ++jj) {
                const int k0 = ks * 32 + quad * 8 + 2 * jj;
                const float lo = Wc[(size_t)k0 * HIDDEN + nt * 16 + r];
                const float hi = Wc[(size_t)(k0 + 1) * HIDDEN + nt * 16 + r];
                u.h[jj] = __float22bfloat162_rn(make_float2(lo, hi));
            }
            Wb[ks][nt] = u.s;
        }
    }
    float bias[4], wo[4];
    #pragma unroll
    for (int nt = 0; nt < 4; ++nt) { bias[nt] = bc[nt * 16 + r]; wo[nt] = Wo[nt * 16 + r]; }
    const float bo_s = bo[0];

    const int nc      = listCnt[0];
    const int n_tiles = (nc + 15) / 16;
    const int wid     = (blockIdx.x * 256 + threadIdx.x) >> 6;
    const int nwaves  = gridDim.x * 4;

    for (int tile = wid; tile < n_tiles; tile += nwaves) {
        const int i0  = tile * 16;
        const int row = i0 + r;
        floatx4 acc[4] = {};
        #pragma unroll
        for (int ks = 0; ks < 2; ++ks) {
            float4 f0 = make_float4(0.f, 0.f, 0.f, 0.f), f1 = f0;
            if (row < nc) {
                const float* src = msg_c + (size_t)row * HIDDEN + ks * 32 + quad * 8;
                f0 = *(const float4*)src;
                f1 = *(const float4*)(src + 4);
            }
            short8 ah, al;
            cvt8_split(f0, f1, ah, al);
            #pragma unroll
            for (int nt = 0; nt < 4; ++nt) {
                acc[nt] = __builtin_amdgcn_mfma_f32_16x16x32_bf16(ah, Wb[ks][nt], acc[nt], 0, 0, 0);
                acc[nt] = __builtin_amdgcn_mfma_f32_16x16x32_bf16(al, Wb[ks][nt], acc[nt], 0, 0, 0);
            }
        }
        float res[4];
        #pragma unroll
        for (int gg = 0; gg < 4; ++gg) {
            float part = 0.0f;
            #pragma unroll
            for (int nt = 0; nt < 4; ++nt)
                part += fmaxf(acc[nt][gg] + bias[nt], 0.0f) * wo[nt];
            part += __shfl_xor(part, 1);
            part += __shfl_xor(part, 2);
            part += __shfl_xor(part, 4);
            part += __shfl_xor(part, 8);
            res[gg] = part;
        }
        if (r == 0) {
            #pragma unroll
            for (int gg = 0; gg < 4; ++gg) {
                const int idx = i0 + quad * 4 + gg;
                if (idx < nc)
                    res_c[idx] = 1.0f / (1.0f + __expf(-(res[gg] + bo_s)));
            }
        }
    }
}

// Final map: out[p] = res_c[inv[post[p]]] (res_c is L2-resident, 157 KB).
__global__ __launch_bounds__(256) void k_out(
    const int* __restrict__ post, const int* __restrict__ inv,
    const float* __restrict__ res_c, float* __restrict__ out, int n_posts)
{
    const int p = blockIdx.x * 256 + threadIdx.x;
    if (p < n_posts) out[p] = res_c[inv[post[p]]];
}

extern "C" void kernel_launch(void* const* d_in, const int* in_sizes, int n_in,
                              void* d_out, int out_size, void* d_ws, size_t ws_size,
                              hipStream_t stream) {
    const float* A    = (const float*)d_in[0];
    const int*   ei   = (const int*)  d_in[1];
    const int*   post = (const int*)  d_in[2];
    const float* We   = (const float*)d_in[3];
    const float* be   = (const float*)d_in[4];
    const float* Wc   = (const float*)d_in[5];
    const float* bc   = (const float*)d_in[6];
    const float* Wo   = (const float*)d_in[7];
    const float* bo   = (const float*)d_in[8];
    float* out = (float*)d_out;

    const int n_nodes = in_sizes[0] / NODE_DIM;   // 100000
    const int n_edges = in_sizes[1] / 2;          // 1200000
    const int n_posts = in_sizes[2];              // 50000

    // ---- workspace layout (every region written before read; ~33 MB) ----
    char* p = (char*)d_ws;
    __hip_bfloat16* emb16 = (__hip_bfloat16*)p;  p += (size_t)n_nodes * HIDDEN * 2;  // 12.8 MB
    float* msg_c    = (float*)p;              p += (size_t)n_posts * HIDDEN * 4;     // 12.8 MB
    int*   slots    = (int*)p;                p += (size_t)n_edges * 4;              // 4.8 MB
    int*   flag     = (int*)p;                p += (size_t)n_nodes * 4;              // zeroed
    int*   count    = (int*)p;                p += (size_t)n_nodes * 4;              // zeroed
    int*   listCnt  = (int*)p;                p += 256;                              // zeroed
    unsigned int* partials = (unsigned int*)p; p += 512;                             // zeroed
    unsigned int* bits = (unsigned int*)p;    p += 16384;                            // zeroed
    int*   row_start= (int*)p;                p += (size_t)n_nodes * 4;
    int*   nodelist = (int*)p;                p += (size_t)n_nodes * 4;
    int*   inv      = (int*)p;                p += (size_t)n_nodes * 4;
    float* res_c    = (float*)p;              p += (size_t)n_posts * 4;

    const int* srcs = ei;
    const int* dsts = ei + n_edges;
    const int nb = (n_nodes + SCAN_CHUNK - 1) / SCAN_CHUNK;   // 98
    const int n_tiles = n_nodes / 16;
    const int rem     = n_nodes - n_tiles * 16;

    // flag, count, listCnt, partials, bits are contiguous -> single memset
    hipMemsetAsync(flag, 0, (size_t)n_nodes * 8 + 256 + 512 + 16384, stream);
    k_setflags<<<(n_posts + 255) / 256, 256, 0, stream>>>(post, flag, bits, nodelist, inv, listCnt, n_posts);
    k_encode_mfma<<<(n_tiles + 3) / 4, 256, 0, stream>>>(A, We, be, emb16, n_tiles);
    if (rem > 0)
        k_encode_tail<<<rem, 64, 0, stream>>>(A, We, be, emb16, n_tiles * 16);
    k_count<<<2048, 256, 0, stream>>>(dsts, bits, count, n_edges);
    k_scan_lb<<<nb, 256, 0, stream>>>(count, row_start, partials, n_nodes);
    k_fill<<<2048, 256, 0, stream>>>(srcs, dsts, bits, row_start, slots, n_edges);
    k_gather<<<8192, 256, 0, stream>>>(nodelist, listCnt, row_start, count, slots, emb16, msg_c);
    k_head_mfma<<<1024, 256, 0, stream>>>(listCnt, msg_c, Wc, bc, Wo, bo, res_c);
    k_out<<<(n_posts + 255) / 256, 256, 0, stream>>>(post, inv, res_c, out, n_posts);
}